// Round 11
// baseline (165.540 us; speedup 1.0000x reference)
//
#include <hip/hip_runtime.h>

// Problem constants: b=32, d=256, h=32, w=128
#define BB 32
#define DD 256
#define HW 4096
#define DHW (DD * HW)        // 2^20
#define EPS 1e-5f

typedef float floatx4 __attribute__((ext_vector_type(4)));

// One block per channel d; 1024 threads; thread t owns hw-positions [4t,4t+4)
// across all 32 batches. Stats are block-local (no inter-block comms, no ws).
// Register-staged loads (8 x-float4 + 8 mask-int4 in flight per thread) to
// break the load->wait->consume serialization seen in R10 (VGPR_Count=16,
// 3.1 TB/s). All staging arrays fully unrolled -> static indices -> registers.
__global__ void __launch_bounds__(1024)
channel_kernel(const float* __restrict__ x, const int* __restrict__ mask,
               const float* __restrict__ gamma, const float* __restrict__ beta,
               float* __restrict__ out) {
    const int d = blockIdx.x;            // channel
    const int tid = threadIdx.x;         // 0..1023
    const int wave = tid >> 6, lane = tid & 63;

    const float4* __restrict__ xv4 = reinterpret_cast<const float4*>(x);
    const int4*   __restrict__ mv4 = reinterpret_cast<const int4*>(mask);
    const int xbase = d * 1024 + tid;    // float4 index of (b=0, d, 4*tid)

    // ---- Phase A: masked accumulation, 16 loads in flight per thread ----
    float sum = 0.f, sq = 0.f, cnt = 0.f;
#pragma unroll
    for (int g = 0; g < 4; ++g) {        // 4 groups x 8 batches
        float4 xs[8];
        int4   ms[8];
#pragma unroll
        for (int k = 0; k < 8; ++k) {    // issue 16 independent loads
            const int b = g * 8 + k;
            xs[k] = xv4[b * (DHW / 4) + xbase];
            ms[k] = mv4[b * 1024 + tid];
        }
#pragma unroll
        for (int k = 0; k < 8; ++k) {    // consume
            const float vx = ms[k].x ? 0.f : xs[k].x;
            const float vy = ms[k].y ? 0.f : xs[k].y;
            const float vz = ms[k].z ? 0.f : xs[k].z;
            const float vw = ms[k].w ? 0.f : xs[k].w;
            sum += vx + vy + vz + vw;
            sq  += vx * vx + vy * vy + vz * vz + vw * vw;
            cnt += (ms[k].x ? 0.f : 1.f) + (ms[k].y ? 0.f : 1.f)
                 + (ms[k].z ? 0.f : 1.f) + (ms[k].w ? 0.f : 1.f);
        }
    }

    // ---- Phase B: block reduce (1024 -> 1), compute scale/bias ----
    __shared__ float rsum[16], rsq[16], rcnt[16];
    __shared__ float s_scale, s_bias;
#pragma unroll
    for (int off = 32; off > 0; off >>= 1) {
        sum += __shfl_down(sum, off);
        sq  += __shfl_down(sq, off);
        cnt += __shfl_down(cnt, off);
    }
    if (lane == 0) { rsum[wave] = sum; rsq[wave] = sq; rcnt[wave] = cnt; }
    __syncthreads();
    if (tid < 16) {
        float ts = rsum[tid], tq = rsq[tid], tc = rcnt[tid];
#pragma unroll
        for (int off = 8; off > 0; off >>= 1) {
            ts += __shfl_down(ts, off, 16);
            tq += __shfl_down(tq, off, 16);
            tc += __shfl_down(tc, off, 16);
        }
        if (tid == 0) {
            tc = fmaxf(tc, 1.0f);
            const float mean = ts / tc;
            const float var = fmaxf(tq / tc - mean * mean, 0.0f);
            const float sc = rsqrtf(var + EPS) * gamma[d];
            s_scale = sc;
            s_bias = beta[d] - mean * sc;
        }
    }
    __syncthreads();
    const float sc = s_scale, bi = s_bias;

    // ---- Phase C: re-read own 512 KB (in-kernel L3 hit) + nt-store out ----
    floatx4* __restrict__ ov4 = reinterpret_cast<floatx4*>(out);
#pragma unroll
    for (int g = 0; g < 4; ++g) {
        float4 xs[8];
        int4   ms[8];
#pragma unroll
        for (int k = 0; k < 8; ++k) {
            const int b = g * 8 + k;
            xs[k] = xv4[b * (DHW / 4) + xbase];
            ms[k] = mv4[b * 1024 + tid];
        }
#pragma unroll
        for (int k = 0; k < 8; ++k) {
            const int b = g * 8 + k;
            floatx4 o;
            o.x = ms[k].x ? xs[k].x : xs[k].x * sc + bi;
            o.y = ms[k].y ? xs[k].y : xs[k].y * sc + bi;
            o.z = ms[k].z ? xs[k].z : xs[k].z * sc + bi;
            o.w = ms[k].w ? xs[k].w : xs[k].w * sc + bi;
            __builtin_nontemporal_store(o, &ov4[b * (DHW / 4) + xbase]);
        }
    }
}

extern "C" void kernel_launch(void* const* d_in, const int* in_sizes, int n_in,
                              void* d_out, int out_size, void* d_ws, size_t ws_size,
                              hipStream_t stream) {
    const float* x     = (const float*)d_in[0];
    const int*   mask  = (const int*)d_in[1];
    const float* gamma = (const float*)d_in[2];
    const float* beta  = (const float*)d_in[3];
    float* out = (float*)d_out;

    channel_kernel<<<DD, 1024, 0, stream>>>(x, mask, gamma, beta, out);
}

// Round 12
// 65.543 us; speedup vs baseline: 2.5257x; 2.5257x over previous
//
#include <hip/hip_runtime.h>

// Problem constants: b=32, d=256, h=32, w=128
#define BB 32
#define DD 256
#define HW 4096
#define DHW (DD * HW)        // 2^20
#define EPS 1e-5f

typedef float floatx4 __attribute__((ext_vector_type(4)));

// One block per channel d; 1024 threads; thread t owns hw-positions [4t,4t+4)
// across all 32 batches. Stats are block-local (no inter-block comms, no ws).
// Register-staged loads: 8 x-float4 + 8 mask-int4 in flight per thread.
// CRITICAL (R11 lesson): outer loop must NOT unroll (one staging group live),
// and launch_bounds must grant the 128-VGPR budget (2nd arg = 4 waves/EU).
__global__ void __launch_bounds__(1024, 4)
channel_kernel(const float* __restrict__ x, const int* __restrict__ mask,
               const float* __restrict__ gamma, const float* __restrict__ beta,
               float* __restrict__ out) {
    const int d = blockIdx.x;            // channel
    const int tid = threadIdx.x;         // 0..1023
    const int wave = tid >> 6, lane = tid & 63;

    const float4* __restrict__ xv4 = reinterpret_cast<const float4*>(x);
    const int4*   __restrict__ mv4 = reinterpret_cast<const int4*>(mask);
    const int xbase = d * 1024 + tid;    // float4 index of (b=0, d, 4*tid)

    // ---- Phase A: masked accumulation, 16 loads in flight per thread ----
    float sum = 0.f, sq = 0.f, cnt = 0.f;
#pragma unroll 1
    for (int g = 0; g < 4; ++g) {        // 4 groups x 8 batches — NOT unrolled
        float4 xs[8];
        int4   ms[8];
#pragma unroll
        for (int k = 0; k < 8; ++k) {    // issue 16 independent loads
            const int b = g * 8 + k;
            xs[k] = xv4[b * (DHW / 4) + xbase];
            ms[k] = mv4[b * 1024 + tid];
        }
#pragma unroll
        for (int k = 0; k < 8; ++k) {    // consume
            const float vx = ms[k].x ? 0.f : xs[k].x;
            const float vy = ms[k].y ? 0.f : xs[k].y;
            const float vz = ms[k].z ? 0.f : xs[k].z;
            const float vw = ms[k].w ? 0.f : xs[k].w;
            sum += vx + vy + vz + vw;
            sq  += vx * vx + vy * vy + vz * vz + vw * vw;
            cnt += (ms[k].x ? 0.f : 1.f) + (ms[k].y ? 0.f : 1.f)
                 + (ms[k].z ? 0.f : 1.f) + (ms[k].w ? 0.f : 1.f);
        }
    }

    // ---- Phase B: block reduce (1024 -> 1), compute scale/bias ----
    __shared__ float rsum[16], rsq[16], rcnt[16];
    __shared__ float s_scale, s_bias;
#pragma unroll
    for (int off = 32; off > 0; off >>= 1) {
        sum += __shfl_down(sum, off);
        sq  += __shfl_down(sq, off);
        cnt += __shfl_down(cnt, off);
    }
    if (lane == 0) { rsum[wave] = sum; rsq[wave] = sq; rcnt[wave] = cnt; }
    __syncthreads();
    if (tid < 16) {
        float ts = rsum[tid], tq = rsq[tid], tc = rcnt[tid];
#pragma unroll
        for (int off = 8; off > 0; off >>= 1) {
            ts += __shfl_down(ts, off, 16);
            tq += __shfl_down(tq, off, 16);
            tc += __shfl_down(tc, off, 16);
        }
        if (tid == 0) {
            tc = fmaxf(tc, 1.0f);
            const float mean = ts / tc;
            const float var = fmaxf(tq / tc - mean * mean, 0.0f);
            const float sc = rsqrtf(var + EPS) * gamma[d];
            s_scale = sc;
            s_bias = beta[d] - mean * sc;
        }
    }
    __syncthreads();
    const float sc = s_scale, bi = s_bias;

    // ---- Phase C: re-read own 512 KB (in-kernel L3 hit) + nt-store out ----
    floatx4* __restrict__ ov4 = reinterpret_cast<floatx4*>(out);
#pragma unroll 1
    for (int g = 0; g < 4; ++g) {        // NOT unrolled
        float4 xs[8];
        int4   ms[8];
#pragma unroll
        for (int k = 0; k < 8; ++k) {
            const int b = g * 8 + k;
            xs[k] = xv4[b * (DHW / 4) + xbase];
            ms[k] = mv4[b * 1024 + tid];
        }
#pragma unroll
        for (int k = 0; k < 8; ++k) {
            const int b = g * 8 + k;
            floatx4 o;
            o.x = ms[k].x ? xs[k].x : xs[k].x * sc + bi;
            o.y = ms[k].y ? xs[k].y : xs[k].y * sc + bi;
            o.z = ms[k].z ? xs[k].z : xs[k].z * sc + bi;
            o.w = ms[k].w ? xs[k].w : xs[k].w * sc + bi;
            __builtin_nontemporal_store(o, &ov4[b * (DHW / 4) + xbase]);
        }
    }
}

extern "C" void kernel_launch(void* const* d_in, const int* in_sizes, int n_in,
                              void* d_out, int out_size, void* d_ws, size_t ws_size,
                              hipStream_t stream) {
    const float* x     = (const float*)d_in[0];
    const int*   mask  = (const int*)d_in[1];
    const float* gamma = (const float*)d_in[2];
    const float* beta  = (const float*)d_in[3];
    float* out = (float*)d_out;

    channel_kernel<<<DD, 1024, 0, stream>>>(x, mask, gamma, beta, out);
}